// Round 10
// baseline (143.438 us; speedup 1.0000x reference)
//
#include <hip/hip_runtime.h>
#include <hip/hip_bf16.h>
#include <math.h>

#define IN_DIM 256
#define HD     512   // NUM_HEADS * OUT_DIM
#define NHEADS 8
#define DH     64
#define NSEQ   1024
#define BATCH  8

#define QSCALE 0.18033688011112042f   // 0.125 * log2(e): S in log2 domain

typedef unsigned short u16;
typedef unsigned int   u32;
typedef short bf16x8 __attribute__((ext_vector_type(8)));
typedef float f32x4  __attribute__((ext_vector_type(4)));

#if __has_builtin(__builtin_amdgcn_exp2f)
#define EXP2(x) __builtin_amdgcn_exp2f(x)
#else
#define EXP2(x) __expf(0.69314718056f * (x))
#endif

static __device__ __forceinline__ u16 f2bf(float x) {
    u32 u = __builtin_bit_cast(u32, x);
    u += 0x7FFFu + ((u >> 16) & 1u);     // RNE
    return (u16)(u >> 16);
}
static __device__ __forceinline__ float bf2f(u16 x) {
    return __builtin_bit_cast(float, ((u32)x) << 16);
}
static __device__ __forceinline__ u32 pk(u16 a, u16 b) {
    return (u32)a | ((u32)b << 16);
}
static __device__ __forceinline__ u32 cvtpk(float a, float b) {
    __hip_bfloat162 t = __float22bfloat162_rn(make_float2(a, b));
    u32 r; __builtin_memcpy(&r, &t, 4);
    return r;
}

// ============================================================
// W transpose: 96 blocks. W [K=256][N=512] fp32 -> Wt [N][K] bf16 (x3)
// ============================================================
__global__ __launch_bounds__(256)
void wtrans_kernel(const float* __restrict__ Wq, const float* __restrict__ Wk,
                   const float* __restrict__ Wv, u16* __restrict__ Wt)
{
    __shared__ float tile[64 * 65];
    const int bid = blockIdx.x, tid = threadIdx.x;
    const int k0 = (bid & 3) * 64, n0 = ((bid >> 2) & 7) * 64, wsel = bid >> 5;
    const float* W = (wsel == 0) ? Wq : (wsel == 1) ? Wk : Wv;
    u16* Out = Wt + (size_t)wsel * HD * IN_DIM;

    const int r = tid >> 2, c0 = (tid & 3) * 16;
#pragma unroll
    for (int j = 0; j < 16; j += 4) {
        float4 v = *(const float4*)(W + (size_t)(k0 + r) * HD + n0 + c0 + j);
        tile[r * 65 + c0 + j + 0] = v.x; tile[r * 65 + c0 + j + 1] = v.y;
        tile[r * 65 + c0 + j + 2] = v.z; tile[r * 65 + c0 + j + 3] = v.w;
    }
    __syncthreads();
    const int n = tid >> 2, ks = (tid & 3) * 16;
    u16 o[16];
#pragma unroll
    for (int j = 0; j < 16; ++j) o[j] = f2bf(tile[(ks + j) * 65 + n]);
    uint4 u0, u1;
    u0.x = pk(o[0], o[1]);   u0.y = pk(o[2], o[3]);
    u0.z = pk(o[4], o[5]);   u0.w = pk(o[6], o[7]);
    u1.x = pk(o[8], o[9]);   u1.y = pk(o[10], o[11]);
    u1.z = pk(o[12], o[13]); u1.w = pk(o[14], o[15]);
    u16* dst = Out + (size_t)(n0 + n) * IN_DIM + k0 + ks;
    *(uint4*)(dst) = u0;
    *(uint4*)(dst + 8) = u1;
}

// ============================================================
// Fused QKV GEMM + mask build, grid (128, 10):
//  y<8:  GEMM m-tile 64 x head y (BM=64, acc 48 VGPR)
//  y>=8: adj -> MaddT[key][q] bf16 {0, -3.39e38}  (256 blocks)
// Mask work overlaps GEMM instead of serializing ahead of it.
// ============================================================
__global__ __launch_bounds__(256, 4)
void gemm_mask_kernel(const float* __restrict__ h, const u16* __restrict__ Wt,
                      const int* __restrict__ adj,
                      const float* __restrict__ bq, const float* __restrict__ bk,
                      const float* __restrict__ bv,
                      u16* __restrict__ Qg, u16* __restrict__ Kg,
                      u16* __restrict__ Vtg, u16* __restrict__ MaddT)
{
    __shared__ u16 pool[64 * 64 + 3 * 64 * 64];   // 32 KB
    const int tid = threadIdx.x;

    if (blockIdx.y >= 8) {
        // ---- adjacency transpose to bf16 additive mask ----
        int* tile = (int*)pool;              // [64][65] ints = 16.6 KB
        const int abid = (blockIdx.y - 8) * 128 + blockIdx.x;   // 0..255
        const int tR = abid >> 4, tC = abid & 15;   // q-tile, key-tile
        const int r = tid >> 2, cg = (tid & 3) * 16;
        const int* src = adj + (size_t)(tR * 64 + r) * NSEQ + tC * 64 + cg;
#pragma unroll
        for (int j = 0; j < 16; j += 4) {
            int4 a = *(const int4*)(src + j);
            tile[r * 65 + cg + j + 0] = a.x; tile[r * 65 + cg + j + 1] = a.y;
            tile[r * 65 + cg + j + 2] = a.z; tile[r * 65 + cg + j + 3] = a.w;
        }
        __syncthreads();
        const int kk = tid >> 2, qg = (tid & 3) * 16;
        u16 o[16];
#pragma unroll
        for (int j = 0; j < 16; ++j)
            o[j] = (tile[(qg + j) * 65 + kk] == 0) ? (u16)0xFF7F : (u16)0;
        uint4 u0, u1;
        u0.x = pk(o[0], o[1]);   u0.y = pk(o[2], o[3]);
        u0.z = pk(o[4], o[5]);   u0.w = pk(o[6], o[7]);
        u1.x = pk(o[8], o[9]);   u1.y = pk(o[10], o[11]);
        u1.z = pk(o[12], o[13]); u1.w = pk(o[14], o[15]);
        u16* dst = MaddT + (size_t)(tC * 64 + kk) * NSEQ + tR * 64 + qg;
        *(uint4*)(dst) = u0;
        *(uint4*)(dst + 8) = u1;
        return;
    }

    // ---------------- GEMM branch ----------------
    u16* As = pool;
    u16* Bs = pool + 64 * 64;

    const int m0 = blockIdx.x * 64;
    const int hh = blockIdx.y;
    const int n0 = hh * 64;

    const int w = tid >> 6, lane = tid & 63, l15 = lane & 15, quad = lane >> 4;
    const int sw = l15 & 7;

    f32x4 acc[3][4];
#pragma unroll
    for (int wh = 0; wh < 3; ++wh)
#pragma unroll
        for (int t = 0; t < 4; ++t) acc[wh][t] = (f32x4){0.f, 0.f, 0.f, 0.f};

    const int arow = tid >> 2, acg = (tid & 3) * 2;     // A: row, 2 granules
    const int brow = tid & 63, bgrp = tid >> 6;         // B: row, 6 granule-cols
    const float* srcA = h + (size_t)(m0 + arow) * IN_DIM;

    for (int kk = 0; kk < IN_DIM; kk += 64) {
        __syncthreads();
#pragma unroll
        for (int g = 0; g < 2; ++g) {
            const float* p = srcA + kk + (acg + g) * 8;
            float4 v0 = *(const float4*)(p);
            float4 v1 = *(const float4*)(p + 4);
            uint4 u;
            u.x = cvtpk(v0.x, v0.y); u.y = cvtpk(v0.z, v0.w);
            u.z = cvtpk(v1.x, v1.y); u.w = cvtpk(v1.z, v1.w);
            *(uint4*)&As[arow * 64 + (((acg + g) ^ (arow & 7)) * 8)] = u;
        }
#pragma unroll
        for (int i = 0; i < 6; ++i) {
            const int gc = bgrp * 6 + i;            // 0..23
            const int wh = gc >> 3, c8 = gc & 7;
            *(uint4*)&Bs[wh * 4096 + brow * 64 + ((c8 ^ (brow & 7)) * 8)] =
                *(const uint4*)(Wt + (size_t)wh * HD * IN_DIM +
                                (size_t)(n0 + brow) * IN_DIM + kk + c8 * 8);
        }
        __syncthreads();
        const int ra = (w * 16 + l15) * 64;
        bf16x8 a0 = *(const bf16x8*)&As[ra + ((quad ^ sw) * 8)];
        bf16x8 a1 = *(const bf16x8*)&As[ra + (((4 + quad) ^ sw) * 8)];
#pragma unroll
        for (int t = 0; t < 4; ++t) {
            const int rb = (t * 16 + l15) * 64;
#pragma unroll
            for (int wh = 0; wh < 3; ++wh) {
                bf16x8 b0 = *(const bf16x8*)&Bs[wh * 4096 + rb + ((quad ^ sw) * 8)];
                bf16x8 b1 = *(const bf16x8*)&Bs[wh * 4096 + rb + (((4 + quad) ^ sw) * 8)];
                acc[wh][t] = __builtin_amdgcn_mfma_f32_16x16x32_bf16(a0, b0, acc[wh][t], 0, 0, 0);
                acc[wh][t] = __builtin_amdgcn_mfma_f32_16x16x32_bf16(a1, b1, acc[wh][t], 0, 0, 0);
            }
        }
    }

    // ---- Q and K epilogues: LDS re-tile, full-line coalesced stores ----
    for (int which = 0; which < 2; ++which) {
        u16* T = pool;   // [64][72]
        const float* bias = (which == 0) ? bq : bk;
        u16* Out = (which == 0) ? Qg : Kg;
        const float scale = (which == 0) ? QSCALE : 1.0f;
        __syncthreads();
#pragma unroll
        for (int t = 0; t < 4; ++t) {
            const float bvv = bias[n0 + t * 16 + l15];
            const int rowb = w * 16 + quad * 4;
#pragma unroll
            for (int r = 0; r < 4; ++r)
                T[(rowb + r) * 72 + t * 16 + l15] =
                    f2bf((acc[which][t][r] + bvv) * scale);
        }
        __syncthreads();
        const int row = tid >> 2, qc = (tid & 3) * 16;
        u16* dst = Out + (size_t)(m0 + row) * HD + n0 + qc;
        const u16* srcT = &T[row * 72 + qc];
        *(uint4*)(dst)     = *(const uint4*)(srcT);
        *(uint4*)(dst + 8) = *(const uint4*)(srcT + 8);
    }

    // ---- V epilogue: transpose + chunk permutation (BM=64 = 1 chunk) ----
    {
        u16* T = pool;   // [64][72]
        __syncthreads();
#pragma unroll
        for (int t = 0; t < 4; ++t) {
            const float bvv = bv[n0 + t * 16 + l15];
            const int trow = (t * 16 + l15) * 72;
#pragma unroll
            for (int r = 0; r < 4; ++r)
                T[trow + (quad * 4 + r) * 4 + w] = f2bf(acc[2][t][r] + bvv);
        }
        __syncthreads();
        const int b = m0 >> 10, nloc = m0 & 1023;
        const int d = tid >> 2, c = (tid & 3) * 16;
        u16* dst = Vtg + ((size_t)(b * NHEADS + hh) * DH + d) * NSEQ + nloc + c;
        *(uint4*)(dst)     = *(uint4*)&T[d * 72 + c];
        *(uint4*)(dst + 8) = *(uint4*)&T[d * 72 + c + 8];
    }
}

// ============================================================
// Fused masked attention, no-max softmax, QT=64:
// grid (64 bh, 16 qt) — bh fastest: all 16 qt of a head on one XCD;
// per-XCD L2 set = 8 heads' K/V (2 MB) + bf16 mask (2 MB) = resident.
// 256 threads (4 waves x 16 q-rows); LDS 40 KB -> 4 blocks/CU.
// ============================================================
__global__ __launch_bounds__(256, 4)
void attn_kernel(const u16* __restrict__ MaddT, const u16* __restrict__ Qg,
                 const u16* __restrict__ Kg, const u16* __restrict__ Vtg,
                 float* __restrict__ out)
{
    __shared__ u16 Ks[2][64 * 64];
    __shared__ u16 Vs[2][64 * 64];     // [d][pos]  (keys permuted per chunk)
    __shared__ u16 Ps[64 * 64];        // [q][pos], XOR-swizzled 16B granules

    const int tid = threadIdx.x;
    const int w = tid >> 6, lane = tid & 63, l15 = lane & 15, quad = lane >> 4;
    const int bh = blockIdx.x, qt = blockIdx.y;
    const int b = bh >> 3;
    const int n0 = qt * 64;
    const size_t rowbase = (size_t)b * NSEQ;
    const int colbase = (bh & 7) * DH;
    const int sw = l15 & 7;

    // Q A-frags (bf16, pre-scaled by 0.125*log2e)
    const u16* qrow = Qg + (rowbase + n0 + w * 16 + l15) * HD + colbase;
    const bf16x8 qa0 = *(const bf16x8*)(qrow + quad * 8);
    const bf16x8 qa1 = *(const bf16x8*)(qrow + 32 + quad * 8);

    // staging: 256 thr -> 64 rows x 4 granule-pairs (32B/thread of K and V)
    const int srow = tid >> 2, cp = (tid & 3) * 2;
    const int swc0 = ((cp ^ (srow & 7)) * 8), swc1 = (((cp + 1) ^ (srow & 7)) * 8);
    const u16* kgp = Kg + (rowbase + srow) * HD + colbase + cp * 8;
    const u16* vgp = Vtg + ((size_t)bh * DH + srow) * NSEQ + cp * 8;
    // bf16 mask adds: MaddT[key][q]; key = ch*64+t*16+l15, q = n0+w*16+quad*4+r
    const u16* mgp = MaddT + (size_t)l15 * NSEQ + n0 + w * 16 + quad * 4;

    uint4 kG0 = *(const uint4*)kgp, kG1 = *(const uint4*)(kgp + 8);
    uint4 vG0 = *(const uint4*)vgp, vG1 = *(const uint4*)(vgp + 8);
    ushort4 mG[4];
#pragma unroll
    for (int t = 0; t < 4; ++t) mG[t] = *(const ushort4*)(mgp + (size_t)(t * 16) * NSEQ);

    *(uint4*)&Ks[0][srow * 64 + swc0] = kG0;
    *(uint4*)&Ks[0][srow * 64 + swc1] = kG1;
    *(uint4*)&Vs[0][srow * 64 + swc0] = vG0;
    *(uint4*)&Vs[0][srow * 64 + swc1] = vG1;
    __syncthreads();

    float lrow[4] = {0.f, 0.f, 0.f, 0.f};
    f32x4 O[4];
#pragma unroll
    for (int t = 0; t < 4; ++t) O[t] = (f32x4){0.f, 0.f, 0.f, 0.f};

    const int pwbase = (w * 16 + quad * 4) * 64;
    const int parow  = (w * 16 + l15) * 64;

    for (int ch = 0; ch < 16; ++ch) {
        const int cur = ch & 1;

        // C-init from bf16 mask adds (current chunk)
        f32x4 s4[4];
#pragma unroll
        for (int t = 0; t < 4; ++t)
            s4[t] = (f32x4){bf2f(mG[t].x), bf2f(mG[t].y),
                            bf2f(mG[t].z), bf2f(mG[t].w)};

        // prefetch next chunk into regs (overlaps MFMA)
        if (ch < 15) {
            kG0 = *(const uint4*)(kgp + (size_t)(ch + 1) * 64 * HD);
            kG1 = *(const uint4*)(kgp + (size_t)(ch + 1) * 64 * HD + 8);
            vG0 = *(const uint4*)(vgp + (ch + 1) * 64);
            vG1 = *(const uint4*)(vgp + (ch + 1) * 64 + 8);
#pragma unroll
            for (int t = 0; t < 4; ++t)
                mG[t] = *(const ushort4*)(mgp + ((size_t)(ch + 1) * 64 + t * 16) * NSEQ);
        }

        // S(log2) = Q K^T + mask
#pragma unroll
        for (int t = 0; t < 4; ++t) {
            const int rb = (t * 16 + l15) * 64;
            bf16x8 kb0 = *(const bf16x8*)&Ks[cur][rb + ((quad ^ sw) * 8)];
            bf16x8 kb1 = *(const bf16x8*)&Ks[cur][rb + (((4 + quad) ^ sw) * 8)];
            s4[t] = __builtin_amdgcn_mfma_f32_16x16x32_bf16(qa0, kb0, s4[t], 0, 0, 0);
            s4[t] = __builtin_amdgcn_mfma_f32_16x16x32_bf16(qa1, kb1, s4[t], 0, 0, 0);
        }

        if (ch < 15) {
            *(uint4*)&Ks[1 - cur][srow * 64 + swc0] = kG0;
            *(uint4*)&Ks[1 - cur][srow * 64 + swc1] = kG1;
            *(uint4*)&Vs[1 - cur][srow * 64 + swc0] = vG0;
            *(uint4*)&Vs[1 - cur][srow * 64 + swc1] = vG1;
        }

        // p = exp2(s); pack pairs; one b64 store per row
#pragma unroll
        for (int r = 0; r < 4; ++r) {
            float p0 = EXP2(s4[0][r]);
            float p1 = EXP2(s4[1][r]);
            float p2 = EXP2(s4[2][r]);
            float p3 = EXP2(s4[3][r]);
            lrow[r] += (p0 + p1) + (p2 + p3);
            uint2 pw;
            pw.x = cvtpk(p0, p1);
            pw.y = cvtpk(p2, p3);
            const int q7 = (quad * 4 + r) & 7;
            *(uint2*)&Ps[pwbase + r * 64 + (((l15 >> 1) ^ q7) * 8) + (l15 & 1) * 4] = pw;
        }

        // O += P V  (wave-private Ps rows: no barrier)
        {
            bf16x8 pa0 = *(const bf16x8*)&Ps[parow + ((quad ^ sw) * 8)];
            bf16x8 pa1 = *(const bf16x8*)&Ps[parow + (((4 + quad) ^ sw) * 8)];
#pragma unroll
            for (int t = 0; t < 4; ++t) {
                const int rb = (t * 16 + l15) * 64;
                bf16x8 vb0 = *(const bf16x8*)&Vs[cur][rb + ((quad ^ sw) * 8)];
                bf16x8 vb1 = *(const bf16x8*)&Vs[cur][rb + (((4 + quad) ^ sw) * 8)];
                O[t] = __builtin_amdgcn_mfma_f32_16x16x32_bf16(pa0, vb0, O[t], 0, 0, 0);
                O[t] = __builtin_amdgcn_mfma_f32_16x16x32_bf16(pa1, vb1, O[t], 0, 0, 0);
            }
        }
        __syncthreads();
    }

    // l across the 16 column-lanes
#pragma unroll
    for (int d = 1; d < 16; d <<= 1)
#pragma unroll
        for (int r = 0; r < 4; ++r)
            lrow[r] += __shfl_xor(lrow[r], d, 64);

    float inv[4];
#pragma unroll
    for (int r = 0; r < 4; ++r) inv[r] = 1.0f / lrow[r];
#pragma unroll
    for (int t = 0; t < 4; ++t)
#pragma unroll
        for (int r = 0; r < 4; ++r)
            out[(rowbase + n0 + w * 16 + quad * 4 + r) * HD + colbase + t * 16 + l15] =
                O[t][r] * inv[r];
}

// ============================================================
extern "C" void kernel_launch(void* const* d_in, const int* in_sizes, int n_in,
                              void* d_out, int out_size, void* d_ws, size_t ws_size,
                              hipStream_t stream) {
    const int*   adj = (const int*)d_in[0];
    const float* h   = (const float*)d_in[1];
    const float* Wq  = (const float*)d_in[2];
    const float* bq  = (const float*)d_in[3];
    const float* Wk  = (const float*)d_in[4];
    const float* bk  = (const float*)d_in[5];
    const float* Wv  = (const float*)d_in[6];
    const float* bv  = (const float*)d_in[7];
    float* outp = (float*)d_out;

    u16* Wt    = (u16*)d_ws;                                 // 3*512*256 u16
    u16* Qg    = Wt + (size_t)3 * HD * IN_DIM;               // 4 Mi u16 each
    u16* Kg    = Qg + (size_t)BATCH * NSEQ * HD;
    u16* Vtg   = Kg + (size_t)BATCH * NSEQ * HD;
    u16* MaddT = Vtg + (size_t)BATCH * NSEQ * HD;            // 1 Mi u16

    wtrans_kernel<<<96, 256, 0, stream>>>(Wq, Wk, Wv, Wt);
    gemm_mask_kernel<<<dim3(BATCH * NSEQ / 64, 10), 256, 0, stream>>>(
        h, Wt, adj, bq, bk, bv, Qg, Kg, Vtg, MaddT);
    attn_kernel<<<dim3(BATCH * NHEADS, NSEQ / 64), 256, 0, stream>>>(
        MaddT, Qg, Kg, Vtg, outp);
}

// Round 11
// 139.654 us; speedup vs baseline: 1.0271x; 1.0271x over previous
//
#include <hip/hip_runtime.h>
#include <hip/hip_bf16.h>
#include <math.h>

#define IN_DIM 256
#define HD     512   // NUM_HEADS * OUT_DIM
#define NHEADS 8
#define DH     64
#define NSEQ   1024
#define BATCH  8

#define QSCALE 0.18033688011112042f   // 0.125 * log2(e): S in log2 domain

typedef unsigned short u16;
typedef unsigned int   u32;
typedef short bf16x8 __attribute__((ext_vector_type(8)));
typedef float f32x4  __attribute__((ext_vector_type(4)));

#if __has_builtin(__builtin_amdgcn_exp2f)
#define EXP2(x) __builtin_amdgcn_exp2f(x)
#else
#define EXP2(x) __expf(0.69314718056f * (x))
#endif

static __device__ __forceinline__ u16 f2bf(float x) {
    u32 u = __builtin_bit_cast(u32, x);
    u += 0x7FFFu + ((u >> 16) & 1u);     // RNE
    return (u16)(u >> 16);
}
static __device__ __forceinline__ float bf2f(u16 x) {
    return __builtin_bit_cast(float, ((u32)x) << 16);
}
static __device__ __forceinline__ u32 pk(u16 a, u16 b) {
    return (u32)a | ((u32)b << 16);
}
static __device__ __forceinline__ u32 cvtpk(float a, float b) {
    __hip_bfloat162 t = __float22bfloat162_rn(make_float2(a, b));
    u32 r; __builtin_memcpy(&r, &t, 4);
    return r;
}

// ============================================================
// W transpose: 96 blocks. W [K=256][N=512] fp32 -> Wt [N][K] bf16 (x3)
// ============================================================
__global__ __launch_bounds__(256)
void wtrans_kernel(const float* __restrict__ Wq, const float* __restrict__ Wk,
                   const float* __restrict__ Wv, u16* __restrict__ Wt)
{
    __shared__ float tile[64 * 65];
    const int bid = blockIdx.x, tid = threadIdx.x;
    const int k0 = (bid & 3) * 64, n0 = ((bid >> 2) & 7) * 64, wsel = bid >> 5;
    const float* W = (wsel == 0) ? Wq : (wsel == 1) ? Wk : Wv;
    u16* Out = Wt + (size_t)wsel * HD * IN_DIM;

    const int r = tid >> 2, c0 = (tid & 3) * 16;
#pragma unroll
    for (int j = 0; j < 16; j += 4) {
        float4 v = *(const float4*)(W + (size_t)(k0 + r) * HD + n0 + c0 + j);
        tile[r * 65 + c0 + j + 0] = v.x; tile[r * 65 + c0 + j + 1] = v.y;
        tile[r * 65 + c0 + j + 2] = v.z; tile[r * 65 + c0 + j + 3] = v.w;
    }
    __syncthreads();
    const int n = tid >> 2, ks = (tid & 3) * 16;
    u16 o[16];
#pragma unroll
    for (int j = 0; j < 16; ++j) o[j] = f2bf(tile[(ks + j) * 65 + n]);
    uint4 u0, u1;
    u0.x = pk(o[0], o[1]);   u0.y = pk(o[2], o[3]);
    u0.z = pk(o[4], o[5]);   u0.w = pk(o[6], o[7]);
    u1.x = pk(o[8], o[9]);   u1.y = pk(o[10], o[11]);
    u1.z = pk(o[12], o[13]); u1.w = pk(o[14], o[15]);
    u16* dst = Out + (size_t)(n0 + n) * IN_DIM + k0 + ks;
    *(uint4*)(dst) = u0;
    *(uint4*)(dst + 8) = u1;
}

// ============================================================
// Fused QKV GEMM + mask build, grid (128, 10):
//  y<8:  GEMM m-tile 64 x head y (BM=64, acc 48 VGPR)
//  y>=8: adj -> MaddT[key][q] bf16 {0, -3.39e38}  (256 blocks)
// ============================================================
__global__ __launch_bounds__(256, 4)
void gemm_mask_kernel(const float* __restrict__ h, const u16* __restrict__ Wt,
                      const int* __restrict__ adj,
                      const float* __restrict__ bq, const float* __restrict__ bk,
                      const float* __restrict__ bv,
                      u16* __restrict__ Qg, u16* __restrict__ Kg,
                      u16* __restrict__ Vtg, u16* __restrict__ MaddT)
{
    __shared__ u16 pool[64 * 64 + 3 * 64 * 64];   // 32 KB
    const int tid = threadIdx.x;

    if (blockIdx.y >= 8) {
        // ---- adjacency transpose to bf16 additive mask ----
        int* tile = (int*)pool;              // [64][65] ints
        const int abid = (blockIdx.y - 8) * 128 + blockIdx.x;   // 0..255
        const int tR = abid >> 4, tC = abid & 15;   // q-tile, key-tile
        const int r = tid >> 2, cg = (tid & 3) * 16;
        const int* src = adj + (size_t)(tR * 64 + r) * NSEQ + tC * 64 + cg;
#pragma unroll
        for (int j = 0; j < 16; j += 4) {
            int4 a = *(const int4*)(src + j);
            tile[r * 65 + cg + j + 0] = a.x; tile[r * 65 + cg + j + 1] = a.y;
            tile[r * 65 + cg + j + 2] = a.z; tile[r * 65 + cg + j + 3] = a.w;
        }
        __syncthreads();
        const int kk = tid >> 2, qg = (tid & 3) * 16;
        u16 o[16];
#pragma unroll
        for (int j = 0; j < 16; ++j)
            o[j] = (tile[(qg + j) * 65 + kk] == 0) ? (u16)0xFF7F : (u16)0;
        uint4 u0, u1;
        u0.x = pk(o[0], o[1]);   u0.y = pk(o[2], o[3]);
        u0.z = pk(o[4], o[5]);   u0.w = pk(o[6], o[7]);
        u1.x = pk(o[8], o[9]);   u1.y = pk(o[10], o[11]);
        u1.z = pk(o[12], o[13]); u1.w = pk(o[14], o[15]);
        u16* dst = MaddT + (size_t)(tC * 64 + kk) * NSEQ + tR * 64 + qg;
        *(uint4*)(dst) = u0;
        *(uint4*)(dst + 8) = u1;
        return;
    }

    // ---------------- GEMM branch ----------------
    u16* As = pool;
    u16* Bs = pool + 64 * 64;

    const int m0 = blockIdx.x * 64;
    const int hh = blockIdx.y;
    const int n0 = hh * 64;

    const int w = tid >> 6, lane = tid & 63, l15 = lane & 15, quad = lane >> 4;
    const int sw = l15 & 7;

    f32x4 acc[3][4];
#pragma unroll
    for (int wh = 0; wh < 3; ++wh)
#pragma unroll
        for (int t = 0; t < 4; ++t) acc[wh][t] = (f32x4){0.f, 0.f, 0.f, 0.f};

    const int arow = tid >> 2, acg = (tid & 3) * 2;     // A: row, 2 granules
    const int brow = tid & 63, bgrp = tid >> 6;         // B: row, 6 granule-cols
    const float* srcA = h + (size_t)(m0 + arow) * IN_DIM;

    for (int kk = 0; kk < IN_DIM; kk += 64) {
        __syncthreads();
#pragma unroll
        for (int g = 0; g < 2; ++g) {
            const float* p = srcA + kk + (acg + g) * 8;
            float4 v0 = *(const float4*)(p);
            float4 v1 = *(const float4*)(p + 4);
            uint4 u;
            u.x = cvtpk(v0.x, v0.y); u.y = cvtpk(v0.z, v0.w);
            u.z = cvtpk(v1.x, v1.y); u.w = cvtpk(v1.z, v1.w);
            *(uint4*)&As[arow * 64 + (((acg + g) ^ (arow & 7)) * 8)] = u;
        }
#pragma unroll
        for (int i = 0; i < 6; ++i) {
            const int gc = bgrp * 6 + i;            // 0..23
            const int wh = gc >> 3, c8 = gc & 7;
            *(uint4*)&Bs[wh * 4096 + brow * 64 + ((c8 ^ (brow & 7)) * 8)] =
                *(const uint4*)(Wt + (size_t)wh * HD * IN_DIM +
                                (size_t)(n0 + brow) * IN_DIM + kk + c8 * 8);
        }
        __syncthreads();
        const int ra = (w * 16 + l15) * 64;
        bf16x8 a0 = *(const bf16x8*)&As[ra + ((quad ^ sw) * 8)];
        bf16x8 a1 = *(const bf16x8*)&As[ra + (((4 + quad) ^ sw) * 8)];
#pragma unroll
        for (int t = 0; t < 4; ++t) {
            const int rb = (t * 16 + l15) * 64;
#pragma unroll
            for (int wh = 0; wh < 3; ++wh) {
                bf16x8 b0 = *(const bf16x8*)&Bs[wh * 4096 + rb + ((quad ^ sw) * 8)];
                bf16x8 b1 = *(const bf16x8*)&Bs[wh * 4096 + rb + (((4 + quad) ^ sw) * 8)];
                acc[wh][t] = __builtin_amdgcn_mfma_f32_16x16x32_bf16(a0, b0, acc[wh][t], 0, 0, 0);
                acc[wh][t] = __builtin_amdgcn_mfma_f32_16x16x32_bf16(a1, b1, acc[wh][t], 0, 0, 0);
            }
        }
    }

    // ---- Q and K epilogues: LDS re-tile, full-line coalesced stores ----
    for (int which = 0; which < 2; ++which) {
        u16* T = pool;   // [64][72]
        const float* bias = (which == 0) ? bq : bk;
        u16* Out = (which == 0) ? Qg : Kg;
        const float scale = (which == 0) ? QSCALE : 1.0f;
        __syncthreads();
#pragma unroll
        for (int t = 0; t < 4; ++t) {
            const float bvv = bias[n0 + t * 16 + l15];
            const int rowb = w * 16 + quad * 4;
#pragma unroll
            for (int r = 0; r < 4; ++r)
                T[(rowb + r) * 72 + t * 16 + l15] =
                    f2bf((acc[which][t][r] + bvv) * scale);
        }
        __syncthreads();
        const int row = tid >> 2, qc = (tid & 3) * 16;
        u16* dst = Out + (size_t)(m0 + row) * HD + n0 + qc;
        const u16* srcT = &T[row * 72 + qc];
        *(uint4*)(dst)     = *(const uint4*)(srcT);
        *(uint4*)(dst + 8) = *(const uint4*)(srcT + 8);
    }

    // ---- V epilogue: transpose + chunk permutation (BM=64 = 1 chunk) ----
    {
        u16* T = pool;   // [64][72]
        __syncthreads();
#pragma unroll
        for (int t = 0; t < 4; ++t) {
            const float bvv = bv[n0 + t * 16 + l15];
            const int trow = (t * 16 + l15) * 72;
#pragma unroll
            for (int r = 0; r < 4; ++r)
                T[trow + (quad * 4 + r) * 4 + w] = f2bf(acc[2][t][r] + bvv);
        }
        __syncthreads();
        const int b = m0 >> 10, nloc = m0 & 1023;
        const int d = tid >> 2, c = (tid & 3) * 16;
        u16* dst = Vtg + ((size_t)(b * NHEADS + hh) * DH + d) * NSEQ + nloc + c;
        *(uint4*)(dst)     = *(uint4*)&T[d * 72 + c];
        *(uint4*)(dst + 8) = *(uint4*)&T[d * 72 + c + 8];
    }
}

// ============================================================
// Fused masked attention, no-max softmax, QT=128 (R9 structure)
// + bf16 mask + bh-fastest grid (R10's L2-residency win).
// grid (64 bh, 8 qt), 512 threads (8 waves x 16 q-rows).
// ============================================================
__global__ __launch_bounds__(512, 4)
void attn_kernel(const u16* __restrict__ MaddT, const u16* __restrict__ Qg,
                 const u16* __restrict__ Kg, const u16* __restrict__ Vtg,
                 float* __restrict__ out)
{
    __shared__ u16 Ks[2][64 * 64];
    __shared__ u16 Vs[2][64 * 64];     // [d][pos]  (keys permuted per chunk)
    __shared__ u16 Ps[128 * 64];       // [q][pos], XOR-swizzled 16B granules

    const int tid = threadIdx.x;
    const int w = tid >> 6, lane = tid & 63, l15 = lane & 15, quad = lane >> 4;
    const int bh = blockIdx.x, qt = blockIdx.y;
    const int b = bh >> 3;
    const int n0 = qt * 128;
    const size_t rowbase = (size_t)b * NSEQ;
    const int colbase = (bh & 7) * DH;
    const int sw = l15 & 7;

    // Q A-frags (bf16, pre-scaled by 0.125*log2e)
    const u16* qrow = Qg + (rowbase + n0 + w * 16 + l15) * HD + colbase;
    const bf16x8 qa0 = *(const bf16x8*)(qrow + quad * 8);
    const bf16x8 qa1 = *(const bf16x8*)(qrow + 32 + quad * 8);

    // staging: 512 thr -> 64 rows x 8 granules of 8 u16
    const int srow = tid >> 3, c8w = tid & 7;
    const int swc = ((c8w ^ (srow & 7)) * 8);
    const u16* kgp = Kg + (rowbase + srow) * HD + colbase + c8w * 8;
    const u16* vgp = Vtg + ((size_t)bh * DH + srow) * NSEQ + c8w * 8;
    // bf16 mask adds: MaddT[key][q]; key = ch*64+t*16+l15, q = n0+w*16+quad*4+r
    const u16* mgp = MaddT + (size_t)l15 * NSEQ + n0 + w * 16 + quad * 4;

    uint4 kG = *(const uint4*)kgp;
    uint4 vG = *(const uint4*)vgp;
    ushort4 mG[4];
#pragma unroll
    for (int t = 0; t < 4; ++t) mG[t] = *(const ushort4*)(mgp + (size_t)(t * 16) * NSEQ);

    *(uint4*)&Ks[0][srow * 64 + swc] = kG;
    *(uint4*)&Vs[0][srow * 64 + swc] = vG;
    __syncthreads();

    float lrow[4] = {0.f, 0.f, 0.f, 0.f};
    f32x4 O[4];
#pragma unroll
    for (int t = 0; t < 4; ++t) O[t] = (f32x4){0.f, 0.f, 0.f, 0.f};

    const int pwbase = (w * 16 + quad * 4) * 64;
    const int parow  = (w * 16 + l15) * 64;

    for (int ch = 0; ch < 16; ++ch) {
        const int cur = ch & 1;

        // C-init from bf16 mask adds (current chunk)
        f32x4 s4[4];
#pragma unroll
        for (int t = 0; t < 4; ++t)
            s4[t] = (f32x4){bf2f(mG[t].x), bf2f(mG[t].y),
                            bf2f(mG[t].z), bf2f(mG[t].w)};

        // prefetch next chunk into regs (overlaps MFMA)
        if (ch < 15) {
            kG = *(const uint4*)(kgp + (size_t)(ch + 1) * 64 * HD);
            vG = *(const uint4*)(vgp + (ch + 1) * 64);
#pragma unroll
            for (int t = 0; t < 4; ++t)
                mG[t] = *(const ushort4*)(mgp + ((size_t)(ch + 1) * 64 + t * 16) * NSEQ);
        }

        // S(log2) = Q K^T + mask
#pragma unroll
        for (int t = 0; t < 4; ++t) {
            const int rb = (t * 16 + l15) * 64;
            bf16x8 kb0 = *(const bf16x8*)&Ks[cur][rb + ((quad ^ sw) * 8)];
            bf16x8 kb1 = *(const bf16x8*)&Ks[cur][rb + (((4 + quad) ^ sw) * 8)];
            s4[t] = __builtin_amdgcn_mfma_f32_16x16x32_bf16(qa0, kb0, s4[t], 0, 0, 0);
            s4[t] = __builtin_amdgcn_mfma_f32_16x16x32_bf16(qa1, kb1, s4[t], 0, 0, 0);
        }

        if (ch < 15) {
            *(uint4*)&Ks[1 - cur][srow * 64 + swc] = kG;
            *(uint4*)&Vs[1 - cur][srow * 64 + swc] = vG;
        }

        // p = exp2(s); pack pairs; one b64 store per row
#pragma unroll
        for (int r = 0; r < 4; ++r) {
            float p0 = EXP2(s4[0][r]);
            float p1 = EXP2(s4[1][r]);
            float p2 = EXP2(s4[2][r]);
            float p3 = EXP2(s4[3][r]);
            lrow[r] += (p0 + p1) + (p2 + p3);
            uint2 pw;
            pw.x = cvtpk(p0, p1);
            pw.y = cvtpk(p2, p3);
            const int q7 = (quad * 4 + r) & 7;
            *(uint2*)&Ps[pwbase + r * 64 + (((l15 >> 1) ^ q7) * 8) + (l15 & 1) * 4] = pw;
        }

        // O += P V  (wave-private Ps rows: no barrier)
        {
            bf16x8 pa0 = *(const bf16x8*)&Ps[parow + ((quad ^ sw) * 8)];
            bf16x8 pa1 = *(const bf16x8*)&Ps[parow + (((4 + quad) ^ sw) * 8)];
#pragma unroll
            for (int t = 0; t < 4; ++t) {
                const int rb = (t * 16 + l15) * 64;
                bf16x8 vb0 = *(const bf16x8*)&Vs[cur][rb + ((quad ^ sw) * 8)];
                bf16x8 vb1 = *(const bf16x8*)&Vs[cur][rb + (((4 + quad) ^ sw) * 8)];
                O[t] = __builtin_amdgcn_mfma_f32_16x16x32_bf16(pa0, vb0, O[t], 0, 0, 0);
                O[t] = __builtin_amdgcn_mfma_f32_16x16x32_bf16(pa1, vb1, O[t], 0, 0, 0);
            }
        }
        __syncthreads();
    }

    // l across the 16 column-lanes
#pragma unroll
    for (int d = 1; d < 16; d <<= 1)
#pragma unroll
        for (int r = 0; r < 4; ++r)
            lrow[r] += __shfl_xor(lrow[r], d, 64);

    float inv[4];
#pragma unroll
    for (int r = 0; r < 4; ++r) inv[r] = 1.0f / lrow[r];
#pragma unroll
    for (int t = 0; t < 4; ++t)
#pragma unroll
        for (int r = 0; r < 4; ++r)
            out[(rowbase + n0 + w * 16 + quad * 4 + r) * HD + colbase + t * 16 + l15] =
                O[t][r] * inv[r];
}

// ============================================================
extern "C" void kernel_launch(void* const* d_in, const int* in_sizes, int n_in,
                              void* d_out, int out_size, void* d_ws, size_t ws_size,
                              hipStream_t stream) {
    const int*   adj = (const int*)d_in[0];
    const float* h   = (const float*)d_in[1];
    const float* Wq  = (const float*)d_in[2];
    const float* bq  = (const float*)d_in[3];
    const float* Wk  = (const float*)d_in[4];
    const float* bk  = (const float*)d_in[5];
    const float* Wv  = (const float*)d_in[6];
    const float* bv  = (const float*)d_in[7];
    float* outp = (float*)d_out;

    u16* Wt    = (u16*)d_ws;                                 // 3*512*256 u16
    u16* Qg    = Wt + (size_t)3 * HD * IN_DIM;               // 4 Mi u16 each
    u16* Kg    = Qg + (size_t)BATCH * NSEQ * HD;
    u16* Vtg   = Kg + (size_t)BATCH * NSEQ * HD;
    u16* MaddT = Vtg + (size_t)BATCH * NSEQ * HD;            // 1 Mi u16

    wtrans_kernel<<<96, 256, 0, stream>>>(Wq, Wk, Wv, Wt);
    gemm_mask_kernel<<<dim3(BATCH * NSEQ / 64, 10), 256, 0, stream>>>(
        h, Wt, adj, bq, bk, bv, Qg, Kg, Vtg, MaddT);
    attn_kernel<<<dim3(BATCH * NHEADS, NSEQ / 128), 512, 0, stream>>>(
        MaddT, Qg, Kg, Vtg, outp);
}

// Round 12
// 131.474 us; speedup vs baseline: 1.0910x; 1.0622x over previous
//
#include <hip/hip_runtime.h>
#include <hip/hip_bf16.h>
#include <math.h>

#define IN_DIM 256
#define HD     512   // NUM_HEADS * OUT_DIM
#define NHEADS 8
#define DH     64
#define NSEQ   1024
#define BATCH  8

#define QSCALE 0.18033688011112042f   // 0.125 * log2(e): S in log2 domain

typedef unsigned short u16;
typedef unsigned int   u32;
typedef short bf16x8 __attribute__((ext_vector_type(8)));
typedef float f32x4  __attribute__((ext_vector_type(4)));
typedef float f32x16 __attribute__((ext_vector_type(16)));

#if __has_builtin(__builtin_amdgcn_exp2f)
#define EXP2(x) __builtin_amdgcn_exp2f(x)
#else
#define EXP2(x) __expf(0.69314718056f * (x))
#endif

static __device__ __forceinline__ u16 f2bf(float x) {
    u32 u = __builtin_bit_cast(u32, x);
    u += 0x7FFFu + ((u >> 16) & 1u);     // RNE
    return (u16)(u >> 16);
}
static __device__ __forceinline__ u32 pk(u16 a, u16 b) {
    return (u32)a | ((u32)b << 16);
}
static __device__ __forceinline__ u32 cvtpk(float a, float b) {
    __hip_bfloat162 t = __float22bfloat162_rn(make_float2(a, b));
    u32 r; __builtin_memcpy(&r, &t, 4);
    return r;
}
// 16 bf16 (two uint4) -> f32x16 C-init
static __device__ __forceinline__ f32x16 maskinit(uint4 a, uint4 b) {
    f32x16 c;
    u32 ws[8] = {a.x, a.y, a.z, a.w, b.x, b.y, b.z, b.w};
#pragma unroll
    for (int i = 0; i < 8; ++i) {
        c[2 * i]     = __builtin_bit_cast(float, ws[i] << 16);
        c[2 * i + 1] = __builtin_bit_cast(float, ws[i] & 0xFFFF0000u);
    }
    return c;
}

// ============================================================
// W transpose: 96 blocks. W [K=256][N=512] fp32 -> Wt [N][K] bf16 (x3)
// ============================================================
__global__ __launch_bounds__(256)
void wtrans_kernel(const float* __restrict__ Wq, const float* __restrict__ Wk,
                   const float* __restrict__ Wv, u16* __restrict__ Wt)
{
    __shared__ float tile[64 * 65];
    const int bid = blockIdx.x, tid = threadIdx.x;
    const int k0 = (bid & 3) * 64, n0 = ((bid >> 2) & 7) * 64, wsel = bid >> 5;
    const float* W = (wsel == 0) ? Wq : (wsel == 1) ? Wk : Wv;
    u16* Out = Wt + (size_t)wsel * HD * IN_DIM;

    const int r = tid >> 2, c0 = (tid & 3) * 16;
#pragma unroll
    for (int j = 0; j < 16; j += 4) {
        float4 v = *(const float4*)(W + (size_t)(k0 + r) * HD + n0 + c0 + j);
        tile[r * 65 + c0 + j + 0] = v.x; tile[r * 65 + c0 + j + 1] = v.y;
        tile[r * 65 + c0 + j + 2] = v.z; tile[r * 65 + c0 + j + 3] = v.w;
    }
    __syncthreads();
    const int n = tid >> 2, ks = (tid & 3) * 16;
    u16 o[16];
#pragma unroll
    for (int j = 0; j < 16; ++j) o[j] = f2bf(tile[(ks + j) * 65 + n]);
    uint4 u0, u1;
    u0.x = pk(o[0], o[1]);   u0.y = pk(o[2], o[3]);
    u0.z = pk(o[4], o[5]);   u0.w = pk(o[6], o[7]);
    u1.x = pk(o[8], o[9]);   u1.y = pk(o[10], o[11]);
    u1.z = pk(o[12], o[13]); u1.w = pk(o[14], o[15]);
    u16* dst = Out + (size_t)(n0 + n) * IN_DIM + k0 + ks;
    *(uint4*)(dst) = u0;
    *(uint4*)(dst + 8) = u1;
}

// ============================================================
// Fused QKV GEMM + mask build, grid (128, 10):
//  y<8:  GEMM m-tile 64 x head y (BM=64, acc 48 VGPR)
//  y>=8: adj -> Madd2[q][64*ch + cpos(c)] bf16 {0,-3.39e38}
//        cpos(c) = 32*(c>>5) + 16*((c>>2)&1) + 4*((c>>3)&3) + (c&3)
// V epilogue uses the same cpos permutation (32x32 MFMA layout).
// ============================================================
__global__ __launch_bounds__(256, 4)
void gemm_mask_kernel(const float* __restrict__ h, const u16* __restrict__ Wt,
                      const int* __restrict__ adj,
                      const float* __restrict__ bq, const float* __restrict__ bk,
                      const float* __restrict__ bv,
                      u16* __restrict__ Qg, u16* __restrict__ Kg,
                      u16* __restrict__ Vtg, u16* __restrict__ Madd2)
{
    __shared__ u16 pool[64 * 64 + 3 * 64 * 64];   // 32 KB
    const int tid = threadIdx.x;

    if (blockIdx.y >= 8) {
        // ---- adjacency -> bf16 additive mask, cpos-permuted cols ----
        int* tile = (int*)pool;              // [64][65] ints
        const int abid = (blockIdx.y - 8) * 128 + blockIdx.x;   // 0..255
        const int tR = abid >> 4, tC = abid & 15;   // q-tile, key-chunk
        const int r = tid >> 2, cg = (tid & 3) * 16;
        const int* src = adj + (size_t)(tR * 64 + r) * NSEQ + tC * 64 + cg;
#pragma unroll
        for (int j = 0; j < 16; j += 4) {
            int4 a = *(const int4*)(src + j);
            tile[r * 65 + cg + j + 0] = a.x; tile[r * 65 + cg + j + 1] = a.y;
            tile[r * 65 + cg + j + 2] = a.z; tile[r * 65 + cg + j + 3] = a.w;
        }
        __syncthreads();
        const int q = tid >> 2, p0 = (tid & 3) * 16;
        u16 o[16];
#pragma unroll
        for (int j = 0; j < 16; ++j) {
            const int p = p0 + j;
            const int c = 32 * (p >> 5) + (p & 3) + 4 * ((p >> 4) & 1) + 8 * ((p >> 2) & 3);
            o[j] = (tile[q * 65 + c] == 0) ? (u16)0xFF7F : (u16)0;
        }
        uint4 u0, u1;
        u0.x = pk(o[0], o[1]);   u0.y = pk(o[2], o[3]);
        u0.z = pk(o[4], o[5]);   u0.w = pk(o[6], o[7]);
        u1.x = pk(o[8], o[9]);   u1.y = pk(o[10], o[11]);
        u1.z = pk(o[12], o[13]); u1.w = pk(o[14], o[15]);
        u16* dst = Madd2 + (size_t)(tR * 64 + q) * NSEQ + tC * 64 + p0;
        *(uint4*)(dst) = u0;
        *(uint4*)(dst + 8) = u1;
        return;
    }

    // ---------------- GEMM branch ----------------
    u16* As = pool;
    u16* Bs = pool + 64 * 64;

    const int m0 = blockIdx.x * 64;
    const int hh = blockIdx.y;
    const int n0 = hh * 64;

    const int w = tid >> 6, lane = tid & 63, l15 = lane & 15, quad = lane >> 4;
    const int sw = l15 & 7;

    f32x4 acc[3][4];
#pragma unroll
    for (int wh = 0; wh < 3; ++wh)
#pragma unroll
        for (int t = 0; t < 4; ++t) acc[wh][t] = (f32x4){0.f, 0.f, 0.f, 0.f};

    const int arow = tid >> 2, acg = (tid & 3) * 2;
    const int brow = tid & 63, bgrp = tid >> 6;
    const float* srcA = h + (size_t)(m0 + arow) * IN_DIM;

    for (int kk = 0; kk < IN_DIM; kk += 64) {
        __syncthreads();
#pragma unroll
        for (int g = 0; g < 2; ++g) {
            const float* p = srcA + kk + (acg + g) * 8;
            float4 v0 = *(const float4*)(p);
            float4 v1 = *(const float4*)(p + 4);
            uint4 u;
            u.x = cvtpk(v0.x, v0.y); u.y = cvtpk(v0.z, v0.w);
            u.z = cvtpk(v1.x, v1.y); u.w = cvtpk(v1.z, v1.w);
            *(uint4*)&As[arow * 64 + (((acg + g) ^ (arow & 7)) * 8)] = u;
        }
#pragma unroll
        for (int i = 0; i < 6; ++i) {
            const int gc = bgrp * 6 + i;
            const int wh = gc >> 3, c8 = gc & 7;
            *(uint4*)&Bs[wh * 4096 + brow * 64 + ((c8 ^ (brow & 7)) * 8)] =
                *(const uint4*)(Wt + (size_t)wh * HD * IN_DIM +
                                (size_t)(n0 + brow) * IN_DIM + kk + c8 * 8);
        }
        __syncthreads();
        const int ra = (w * 16 + l15) * 64;
        bf16x8 a0 = *(const bf16x8*)&As[ra + ((quad ^ sw) * 8)];
        bf16x8 a1 = *(const bf16x8*)&As[ra + (((4 + quad) ^ sw) * 8)];
#pragma unroll
        for (int t = 0; t < 4; ++t) {
            const int rb = (t * 16 + l15) * 64;
#pragma unroll
            for (int wh = 0; wh < 3; ++wh) {
                bf16x8 b0 = *(const bf16x8*)&Bs[wh * 4096 + rb + ((quad ^ sw) * 8)];
                bf16x8 b1 = *(const bf16x8*)&Bs[wh * 4096 + rb + (((4 + quad) ^ sw) * 8)];
                acc[wh][t] = __builtin_amdgcn_mfma_f32_16x16x32_bf16(a0, b0, acc[wh][t], 0, 0, 0);
                acc[wh][t] = __builtin_amdgcn_mfma_f32_16x16x32_bf16(a1, b1, acc[wh][t], 0, 0, 0);
            }
        }
    }

    // ---- Q and K epilogues ----
    for (int which = 0; which < 2; ++which) {
        u16* T = pool;   // [64][72]
        const float* bias = (which == 0) ? bq : bk;
        u16* Out = (which == 0) ? Qg : Kg;
        const float scale = (which == 0) ? QSCALE : 1.0f;
        __syncthreads();
#pragma unroll
        for (int t = 0; t < 4; ++t) {
            const float bvv = bias[n0 + t * 16 + l15];
            const int rowb = w * 16 + quad * 4;
#pragma unroll
            for (int r = 0; r < 4; ++r)
                T[(rowb + r) * 72 + t * 16 + l15] =
                    f2bf((acc[which][t][r] + bvv) * scale);
        }
        __syncthreads();
        const int row = tid >> 2, qc = (tid & 3) * 16;
        u16* dst = Out + (size_t)(m0 + row) * HD + n0 + qc;
        const u16* srcT = &T[row * 72 + qc];
        *(uint4*)(dst)     = *(const uint4*)(srcT);
        *(uint4*)(dst + 8) = *(const uint4*)(srcT + 8);
    }

    // ---- V epilogue: transpose + cpos permutation (contig r!) ----
    {
        u16* T = pool;   // [64][72]
        __syncthreads();
        const int cb = 32 * (w >> 1) + 16 * (quad & 1) + 8 * (w & 1) + 4 * (quad >> 1);
#pragma unroll
        for (int t = 0; t < 4; ++t) {
            const float bvv = bv[n0 + t * 16 + l15];
            ushort4 o;
            o.x = f2bf(acc[2][t][0] + bvv);
            o.y = f2bf(acc[2][t][1] + bvv);
            o.z = f2bf(acc[2][t][2] + bvv);
            o.w = f2bf(acc[2][t][3] + bvv);
            *(ushort4*)&T[(t * 16 + l15) * 72 + cb] = o;
        }
        __syncthreads();
        const int b = m0 >> 10, nloc = m0 & 1023;
        const int d = tid >> 2, c = (tid & 3) * 16;
        u16* dst = Vtg + ((size_t)(b * NHEADS + hh) * DH + d) * NSEQ + nloc + c;
        *(uint4*)(dst)     = *(uint4*)&T[d * 72 + c];
        *(uint4*)(dst + 8) = *(uint4*)&T[d * 72 + c + 8];
    }
}

// ============================================================
// Fused masked attention, 32x32x16 MFMA, no-max softmax.
// S^T = K·Q^T (A=K from LDS, B=Q from regs, C-init = mask add);
// p = exp2; P^T written sigma-contiguous; O^T = V^T·P^T.
// grid (64 bh, 8 qt), 256 thr (4 waves x 32 q-rows).
// ============================================================
__global__ __launch_bounds__(256, 2)
void attn_kernel(const u16* __restrict__ Madd2, const u16* __restrict__ Qg,
                 const u16* __restrict__ Kg, const u16* __restrict__ Vtg,
                 float* __restrict__ out)
{
    __shared__ u16 Ks[2][64 * 64];
    __shared__ u16 Vs[2][64 * 64];     // [d][cpos(m)]
    __shared__ u16 Ps[128 * 64];       // [q][sigma(m)], XOR-swizzled granules

    const int tid = threadIdx.x;
    const int w = tid >> 6, lane = tid & 63;
    const int l31 = lane & 31, half = lane >> 5;
    const int bh = blockIdx.x, qt = blockIdx.y;
    const int b = bh >> 3;
    const int n0 = qt * 128;
    const size_t rowbase = (size_t)b * NSEQ;
    const int colbase = (bh & 7) * DH;
    const int q7 = l31 & 7;
    const int qrow = w * 32 + l31;        // LDS q row (0..127)

    // Q B-frags (bf16, pre-scaled): B[k][q] = Q[q=l31][k]
    const u16* qg = Qg + (rowbase + n0 + qrow) * HD + colbase;
    bf16x8 qb[4];
#pragma unroll
    for (int s = 0; s < 4; ++s)
        qb[s] = *(const bf16x8*)(qg + s * 16 + half * 8);

    // staging: 256 thr -> 64 rows x 4 granule-pairs of K and V
    const int srow = tid >> 2, cp = (tid & 3) * 2;
    const int swc0 = ((cp ^ (srow & 7)) * 8), swc1 = (((cp + 1) ^ (srow & 7)) * 8);
    const u16* kgp = Kg + (rowbase + srow) * HD + colbase + cp * 8;
    const u16* vgp = Vtg + ((size_t)bh * DH + srow) * NSEQ + cp * 8;
    // mask row (cols cpos-permuted): lane's own q
    const u16* mrow = Madd2 + (size_t)(n0 + qrow) * NSEQ + half * 16;

    uint4 kG0 = *(const uint4*)kgp, kG1 = *(const uint4*)(kgp + 8);
    uint4 vG0 = *(const uint4*)vgp, vG1 = *(const uint4*)(vgp + 8);
    uint4 mA0 = *(const uint4*)(mrow);
    uint4 mB0 = *(const uint4*)(mrow + 8);
    uint4 mA1 = *(const uint4*)(mrow + 32);
    uint4 mB1 = *(const uint4*)(mrow + 40);

    *(uint4*)&Ks[0][srow * 64 + swc0] = kG0;
    *(uint4*)&Ks[0][srow * 64 + swc1] = kG1;
    *(uint4*)&Vs[0][srow * 64 + swc0] = vG0;
    *(uint4*)&Vs[0][srow * 64 + swc1] = vG1;
    __syncthreads();

    float lrow = 0.f;
    f32x16 O0 = {}, O1 = {};

    for (int ch = 0; ch < 16; ++ch) {
        const int cur = ch & 1;

        // C-init from mask
        f32x16 st0 = maskinit(mA0, mB0);
        f32x16 st1 = maskinit(mA1, mB1);

        // prefetch next chunk
        if (ch < 15) {
            kG0 = *(const uint4*)(kgp + (size_t)(ch + 1) * 64 * HD);
            kG1 = *(const uint4*)(kgp + (size_t)(ch + 1) * 64 * HD + 8);
            vG0 = *(const uint4*)(vgp + (ch + 1) * 64);
            vG1 = *(const uint4*)(vgp + (ch + 1) * 64 + 8);
            const u16* mnext = mrow + (ch + 1) * 64;
            mA0 = *(const uint4*)(mnext);
            mB0 = *(const uint4*)(mnext + 8);
            mA1 = *(const uint4*)(mnext + 32);
            mB1 = *(const uint4*)(mnext + 40);
        }

        // S^T(log2) = K · Q^T + mask
#pragma unroll
        for (int s = 0; s < 4; ++s) {
            const int g = ((s * 2 + half) ^ q7) * 8;
            bf16x8 ka0 = *(const bf16x8*)&Ks[cur][l31 * 64 + g];
            bf16x8 ka1 = *(const bf16x8*)&Ks[cur][(32 + l31) * 64 + g];
            st0 = __builtin_amdgcn_mfma_f32_32x32x16_bf16(ka0, qb[s], st0, 0, 0, 0);
            st1 = __builtin_amdgcn_mfma_f32_32x32x16_bf16(ka1, qb[s], st1, 0, 0, 0);
        }

        if (ch < 15) {
            *(uint4*)&Ks[1 - cur][srow * 64 + swc0] = kG0;
            *(uint4*)&Ks[1 - cur][srow * 64 + swc1] = kG1;
            *(uint4*)&Vs[1 - cur][srow * 64 + swc0] = vG0;
            *(uint4*)&Vs[1 - cur][srow * 64 + swc1] = vG1;
        }

        // p = exp2(s); sigma-contiguous pack: 2x uint4 per key-tile
#pragma unroll
        for (int tile = 0; tile < 2; ++tile) {
            const f32x16 st = tile ? st1 : st0;
            float p[16];
#pragma unroll
            for (int r = 0; r < 16; ++r) p[r] = EXP2(st[r]);
            float ps = 0.f;
#pragma unroll
            for (int r = 0; r < 16; ++r) ps += p[r];
            lrow += ps;
            uint4 w0, w1;
            w0.x = cvtpk(p[0], p[1]);   w0.y = cvtpk(p[2], p[3]);
            w0.z = cvtpk(p[4], p[5]);   w0.w = cvtpk(p[6], p[7]);
            w1.x = cvtpk(p[8], p[9]);   w1.y = cvtpk(p[10], p[11]);
            w1.z = cvtpk(p[12], p[13]); w1.w = cvtpk(p[14], p[15]);
            const int g = tile * 4 + half * 2;
            *(uint4*)&Ps[qrow * 64 + ((g ^ q7) * 8)]       = w0;
            *(uint4*)&Ps[qrow * 64 + (((g + 1) ^ q7) * 8)] = w1;
        }

        // O^T += V^T · P^T  (wave-private Ps rows: no barrier)
#pragma unroll
        for (int s = 0; s < 4; ++s) {
            const int g = ((s * 2 + half) ^ q7) * 8;
            bf16x8 pb = *(const bf16x8*)&Ps[qrow * 64 + g];
            bf16x8 va0 = *(const bf16x8*)&Vs[cur][l31 * 64 + g];
            bf16x8 va1 = *(const bf16x8*)&Vs[cur][(32 + l31) * 64 + g];
            O0 = __builtin_amdgcn_mfma_f32_32x32x16_bf16(va0, pb, O0, 0, 0, 0);
            O1 = __builtin_amdgcn_mfma_f32_32x32x16_bf16(va1, pb, O1, 0, 0, 0);
        }
        __syncthreads();
    }

    // l: lanes l and l+32 hold disjoint key subsets of the same q
    lrow += __shfl_xor(lrow, 32, 64);
    const float inv = 1.0f / lrow;

    float* orow = out + (rowbase + n0 + qrow) * HD + colbase;
#pragma unroll
    for (int g = 0; g < 4; ++g) {
        const int d0 = 4 * half + 8 * g;
        float4 o0, o1;
        o0.x = O0[4 * g + 0] * inv; o0.y = O0[4 * g + 1] * inv;
        o0.z = O0[4 * g + 2] * inv; o0.w = O0[4 * g + 3] * inv;
        o1.x = O1[4 * g + 0] * inv; o1.y = O1[4 * g + 1] * inv;
        o1.z = O1[4 * g + 2] * inv; o1.w = O1[4 * g + 3] * inv;
        *(float4*)(orow + d0)      = o0;
        *(float4*)(orow + 32 + d0) = o1;
    }
}

// ============================================================
extern "C" void kernel_launch(void* const* d_in, const int* in_sizes, int n_in,
                              void* d_out, int out_size, void* d_ws, size_t ws_size,
                              hipStream_t stream) {
    const int*   adj = (const int*)d_in[0];
    const float* h   = (const float*)d_in[1];
    const float* Wq  = (const float*)d_in[2];
    const float* bq  = (const float*)d_in[3];
    const float* Wk  = (const float*)d_in[4];
    const float* bk  = (const float*)d_in[5];
    const float* Wv  = (const float*)d_in[6];
    const float* bv  = (const float*)d_in[7];
    float* outp = (float*)d_out;

    u16* Wt    = (u16*)d_ws;                                 // 3*512*256 u16
    u16* Qg    = Wt + (size_t)3 * HD * IN_DIM;               // 4 Mi u16 each
    u16* Kg    = Qg + (size_t)BATCH * NSEQ * HD;
    u16* Vtg   = Kg + (size_t)BATCH * NSEQ * HD;
    u16* Madd2 = Vtg + (size_t)BATCH * NSEQ * HD;            // 1 Mi u16

    wtrans_kernel<<<96, 256, 0, stream>>>(Wq, Wk, Wv, Wt);
    gemm_mask_kernel<<<dim3(BATCH * NSEQ / 64, 10), 256, 0, stream>>>(
        h, Wt, adj, bq, bk, bv, Qg, Kg, Vtg, Madd2);
    attn_kernel<<<dim3(BATCH * NHEADS, NSEQ / 128), 256, 0, stream>>>(
        Madd2, Qg, Kg, Vtg, outp);
}

// Round 13
// 129.583 us; speedup vs baseline: 1.1069x; 1.0146x over previous
//
#include <hip/hip_runtime.h>
#include <hip/hip_bf16.h>
#include <math.h>

#define IN_DIM 256
#define HD     512   // NUM_HEADS * OUT_DIM
#define NHEADS 8
#define DH     64
#define NSEQ   1024
#define BATCH  8

#define QSCALE 0.18033688011112042f   // 0.125 * log2(e): S in log2 domain

typedef unsigned short u16;
typedef unsigned int   u32;
typedef short bf16x8 __attribute__((ext_vector_type(8)));
typedef float f32x4  __attribute__((ext_vector_type(4)));
typedef float f32x16 __attribute__((ext_vector_type(16)));

#if __has_builtin(__builtin_amdgcn_exp2f)
#define EXP2(x) __builtin_amdgcn_exp2f(x)
#else
#define EXP2(x) __expf(0.69314718056f * (x))
#endif

static __device__ __forceinline__ u16 f2bf(float x) {
    u32 u = __builtin_bit_cast(u32, x);
    u += 0x7FFFu + ((u >> 16) & 1u);     // RNE
    return (u16)(u >> 16);
}
static __device__ __forceinline__ u32 pk(u16 a, u16 b) {
    return (u32)a | ((u32)b << 16);
}
static __device__ __forceinline__ u32 cvtpk(float a, float b) {
    __hip_bfloat162 t = __float22bfloat162_rn(make_float2(a, b));
    u32 r; __builtin_memcpy(&r, &t, 4);
    return r;
}
// 16 bf16 (two uint4) -> f32x16 C-init
static __device__ __forceinline__ f32x16 maskinit(uint4 a, uint4 b) {
    f32x16 c;
    u32 ws[8] = {a.x, a.y, a.z, a.w, b.x, b.y, b.z, b.w};
#pragma unroll
    for (int i = 0; i < 8; ++i) {
        c[2 * i]     = __builtin_bit_cast(float, ws[i] << 16);
        c[2 * i + 1] = __builtin_bit_cast(float, ws[i] & 0xFFFF0000u);
    }
    return c;
}

// ============================================================
// W transpose: 96 blocks. W [K=256][N=512] fp32 -> Wt [N][K] bf16 (x3)
// ============================================================
__global__ __launch_bounds__(256)
void wtrans_kernel(const float* __restrict__ Wq, const float* __restrict__ Wk,
                   const float* __restrict__ Wv, u16* __restrict__ Wt)
{
    __shared__ float tile[64 * 65];
    const int bid = blockIdx.x, tid = threadIdx.x;
    const int k0 = (bid & 3) * 64, n0 = ((bid >> 2) & 7) * 64, wsel = bid >> 5;
    const float* W = (wsel == 0) ? Wq : (wsel == 1) ? Wk : Wv;
    u16* Out = Wt + (size_t)wsel * HD * IN_DIM;

    const int r = tid >> 2, c0 = (tid & 3) * 16;
#pragma unroll
    for (int j = 0; j < 16; j += 4) {
        float4 v = *(const float4*)(W + (size_t)(k0 + r) * HD + n0 + c0 + j);
        tile[r * 65 + c0 + j + 0] = v.x; tile[r * 65 + c0 + j + 1] = v.y;
        tile[r * 65 + c0 + j + 2] = v.z; tile[r * 65 + c0 + j + 3] = v.w;
    }
    __syncthreads();
    const int n = tid >> 2, ks = (tid & 3) * 16;
    u16 o[16];
#pragma unroll
    for (int j = 0; j < 16; ++j) o[j] = f2bf(tile[(ks + j) * 65 + n]);
    uint4 u0, u1;
    u0.x = pk(o[0], o[1]);   u0.y = pk(o[2], o[3]);
    u0.z = pk(o[4], o[5]);   u0.w = pk(o[6], o[7]);
    u1.x = pk(o[8], o[9]);   u1.y = pk(o[10], o[11]);
    u1.z = pk(o[12], o[13]); u1.w = pk(o[14], o[15]);
    u16* dst = Out + (size_t)(n0 + n) * IN_DIM + k0 + ks;
    *(uint4*)(dst) = u0;
    *(uint4*)(dst + 8) = u1;
}

// ============================================================
// Fused QKV GEMM + mask build, grid (128, 10):
//  y<8:  GEMM m-tile 64 x head y — 32x32x16 MFMA, acc 48 VGPR,
//        wave w owns (mh=w&1, nh=w>>1) 32x32 tile of Q,K,V.
//  y>=8: adj -> Madd2[q][64*ch + cpos(c)] bf16 {0,-3.39e38}
//        cpos(c) = 32*(c>>5) + 16*((c>>2)&1) + 4*((c>>3)&3) + (c&3)
// ============================================================
__global__ __launch_bounds__(256, 4)
void gemm_mask_kernel(const float* __restrict__ h, const u16* __restrict__ Wt,
                      const int* __restrict__ adj,
                      const float* __restrict__ bq, const float* __restrict__ bk,
                      const float* __restrict__ bv,
                      u16* __restrict__ Qg, u16* __restrict__ Kg,
                      u16* __restrict__ Vtg, u16* __restrict__ Madd2)
{
    __shared__ u16 pool[64 * 64 + 3 * 64 * 64];   // 32 KB
    const int tid = threadIdx.x;

    if (blockIdx.y >= 8) {
        // ---- adjacency -> bf16 additive mask, cpos-permuted cols ----
        int* tile = (int*)pool;              // [64][65] ints
        const int abid = (blockIdx.y - 8) * 128 + blockIdx.x;   // 0..255
        const int tR = abid >> 4, tC = abid & 15;   // q-tile, key-chunk
        const int r = tid >> 2, cg = (tid & 3) * 16;
        const int* src = adj + (size_t)(tR * 64 + r) * NSEQ + tC * 64 + cg;
#pragma unroll
        for (int j = 0; j < 16; j += 4) {
            int4 a = *(const int4*)(src + j);
            tile[r * 65 + cg + j + 0] = a.x; tile[r * 65 + cg + j + 1] = a.y;
            tile[r * 65 + cg + j + 2] = a.z; tile[r * 65 + cg + j + 3] = a.w;
        }
        __syncthreads();
        const int q = tid >> 2, p0 = (tid & 3) * 16;
        u16 o[16];
#pragma unroll
        for (int j = 0; j < 16; ++j) {
            const int p = p0 + j;
            const int c = 32 * (p >> 5) + (p & 3) + 4 * ((p >> 4) & 1) + 8 * ((p >> 2) & 3);
            o[j] = (tile[q * 65 + c] == 0) ? (u16)0xFF7F : (u16)0;
        }
        uint4 u0, u1;
        u0.x = pk(o[0], o[1]);   u0.y = pk(o[2], o[3]);
        u0.z = pk(o[4], o[5]);   u0.w = pk(o[6], o[7]);
        u1.x = pk(o[8], o[9]);   u1.y = pk(o[10], o[11]);
        u1.z = pk(o[12], o[13]); u1.w = pk(o[14], o[15]);
        u16* dst = Madd2 + (size_t)(tR * 64 + q) * NSEQ + tC * 64 + p0;
        *(uint4*)(dst) = u0;
        *(uint4*)(dst + 8) = u1;
        return;
    }

    // ---------------- GEMM branch (32x32x16) ----------------
    u16* As = pool;
    u16* Bs = pool + 64 * 64;

    const int m0 = blockIdx.x * 64;
    const int hh = blockIdx.y;
    const int n0 = hh * 64;

    const int w = tid >> 6, lane = tid & 63;
    const int l31 = lane & 31, half = lane >> 5;
    const int mh = w & 1, nh = w >> 1;
    const int s7 = l31 & 7;

    f32x16 acc[3] = {};   // Q, K, V 32x32 tiles

    const int arw = tid >> 2, acg = (tid & 3) * 2;
    const int brw = tid & 63, bgrp = tid >> 6;
    const float* srcA = h + (size_t)(m0 + arw) * IN_DIM;

    for (int kk = 0; kk < IN_DIM; kk += 64) {
        __syncthreads();
#pragma unroll
        for (int g = 0; g < 2; ++g) {
            const float* p = srcA + kk + (acg + g) * 8;
            float4 v0 = *(const float4*)(p);
            float4 v1 = *(const float4*)(p + 4);
            uint4 u;
            u.x = cvtpk(v0.x, v0.y); u.y = cvtpk(v0.z, v0.w);
            u.z = cvtpk(v1.x, v1.y); u.w = cvtpk(v1.z, v1.w);
            *(uint4*)&As[arw * 64 + (((acg + g) ^ (arw & 7)) * 8)] = u;
        }
#pragma unroll
        for (int i = 0; i < 6; ++i) {
            const int gc = bgrp * 6 + i;
            const int wh = gc >> 3, c8 = gc & 7;
            *(uint4*)&Bs[wh * 4096 + brw * 64 + ((c8 ^ (brw & 7)) * 8)] =
                *(const uint4*)(Wt + (size_t)wh * HD * IN_DIM +
                                (size_t)(n0 + brw) * IN_DIM + kk + c8 * 8);
        }
        __syncthreads();
        const int arow = (32 * mh + l31) * 64;
        const int brow = (32 * nh + l31) * 64;
#pragma unroll
        for (int s = 0; s < 4; ++s) {
            const int g = ((s * 2 + half) ^ s7) * 8;
            bf16x8 a = *(const bf16x8*)&As[arow + g];
#pragma unroll
            for (int wh = 0; wh < 3; ++wh) {
                bf16x8 b = *(const bf16x8*)&Bs[wh * 4096 + brow + g];
                acc[wh] = __builtin_amdgcn_mfma_f32_32x32x16_bf16(a, b, acc[wh], 0, 0, 0);
            }
        }
    }

    // ---- Q and K epilogues: LDS re-tile, coalesced stores ----
    // C-layout: col = 32*nh + l31, row = 32*mh + 4*half + (r&3) + 8*(r>>2)
    for (int which = 0; which < 2; ++which) {
        u16* T = pool;   // [64][72]
        const float* bias = (which == 0) ? bq : bk;
        u16* Out = (which == 0) ? Qg : Kg;
        const float scale = (which == 0) ? QSCALE : 1.0f;
        const float bvv = bias[n0 + 32 * nh + l31];
        __syncthreads();
#pragma unroll
        for (int r = 0; r < 16; ++r) {
            const int row = 32 * mh + 4 * half + (r & 3) + 8 * (r >> 2);
            T[row * 72 + 32 * nh + l31] = f2bf((acc[which][r] + bvv) * scale);
        }
        __syncthreads();
        const int row = tid >> 2, qc = (tid & 3) * 16;
        u16* dst = Out + (size_t)(m0 + row) * HD + n0 + qc;
        const u16* srcT = &T[row * 72 + qc];
        *(uint4*)(dst)     = *(const uint4*)(srcT);
        *(uint4*)(dst + 8) = *(const uint4*)(srcT + 8);
    }

    // ---- V epilogue: transpose + cpos permutation ----
    // m = 32*mh + 4*half + (r&3) + 8*(r>>2)  ->  pos(m) = 32*mh + 16*half + 4*(r>>2) + (r&3)
    {
        u16* T = pool;   // [64][72]  [d][pos]
        const int d = 32 * nh + l31;
        const float bvv = bv[n0 + d];
        __syncthreads();
#pragma unroll
        for (int g = 0; g < 4; ++g) {
            ushort4 o;
            o.x = f2bf(acc[2][4 * g + 0] + bvv);
            o.y = f2bf(acc[2][4 * g + 1] + bvv);
            o.z = f2bf(acc[2][4 * g + 2] + bvv);
            o.w = f2bf(acc[2][4 * g + 3] + bvv);
            *(ushort4*)&T[d * 72 + 32 * mh + 16 * half + 4 * g] = o;
        }
        __syncthreads();
        const int b = m0 >> 10, nloc = m0 & 1023;
        const int dd = tid >> 2, c = (tid & 3) * 16;
        u16* dst = Vtg + ((size_t)(b * NHEADS + hh) * DH + dd) * NSEQ + nloc + c;
        *(uint4*)(dst)     = *(uint4*)&T[dd * 72 + c];
        *(uint4*)(dst + 8) = *(uint4*)&T[dd * 72 + c + 8];
    }
}

// ============================================================
// Fused masked attention, 32x32x16 MFMA, no-max softmax.
// S^T = K·Q^T (A=K from LDS, B=Q from regs, C-init = mask add);
// p = exp2; P^T written sigma-contiguous; O^T = V^T·P^T.
// grid (64 bh, 8 qt), 256 thr (4 waves x 32 q-rows).
// ============================================================
__global__ __launch_bounds__(256, 2)
void attn_kernel(const u16* __restrict__ Madd2, const u16* __restrict__ Qg,
                 const u16* __restrict__ Kg, const u16* __restrict__ Vtg,
                 float* __restrict__ out)
{
    __shared__ u16 Ks[2][64 * 64];
    __shared__ u16 Vs[2][64 * 64];     // [d][cpos(m)]
    __shared__ u16 Ps[128 * 64];       // [q][sigma(m)], XOR-swizzled granules

    const int tid = threadIdx.x;
    const int w = tid >> 6, lane = tid & 63;
    const int l31 = lane & 31, half = lane >> 5;
    const int bh = blockIdx.x, qt = blockIdx.y;
    const int b = bh >> 3;
    const int n0 = qt * 128;
    const size_t rowbase = (size_t)b * NSEQ;
    const int colbase = (bh & 7) * DH;
    const int q7 = l31 & 7;
    const int qrow = w * 32 + l31;        // LDS q row (0..127)

    // Q B-frags (bf16, pre-scaled): B[k][q] = Q[q=l31][k]
    const u16* qg = Qg + (rowbase + n0 + qrow) * HD + colbase;
    bf16x8 qb[4];
#pragma unroll
    for (int s = 0; s < 4; ++s)
        qb[s] = *(const bf16x8*)(qg + s * 16 + half * 8);

    // staging: 256 thr -> 64 rows x 4 granule-pairs of K and V
    const int srow = tid >> 2, cp = (tid & 3) * 2;
    const int swc0 = ((cp ^ (srow & 7)) * 8), swc1 = (((cp + 1) ^ (srow & 7)) * 8);
    const u16* kgp = Kg + (rowbase + srow) * HD + colbase + cp * 8;
    const u16* vgp = Vtg + ((size_t)bh * DH + srow) * NSEQ + cp * 8;
    // mask row (cols cpos-permuted): lane's own q
    const u16* mrow = Madd2 + (size_t)(n0 + qrow) * NSEQ + half * 16;

    uint4 kG0 = *(const uint4*)kgp, kG1 = *(const uint4*)(kgp + 8);
    uint4 vG0 = *(const uint4*)vgp, vG1 = *(const uint4*)(vgp + 8);
    uint4 mA0 = *(const uint4*)(mrow);
    uint4 mB0 = *(const uint4*)(mrow + 8);
    uint4 mA1 = *(const uint4*)(mrow + 32);
    uint4 mB1 = *(const uint4*)(mrow + 40);

    *(uint4*)&Ks[0][srow * 64 + swc0] = kG0;
    *(uint4*)&Ks[0][srow * 64 + swc1] = kG1;
    *(uint4*)&Vs[0][srow * 64 + swc0] = vG0;
    *(uint4*)&Vs[0][srow * 64 + swc1] = vG1;
    __syncthreads();

    float lrow = 0.f;
    f32x16 O0 = {}, O1 = {};

    for (int ch = 0; ch < 16; ++ch) {
        const int cur = ch & 1;

        // C-init from mask
        f32x16 st0 = maskinit(mA0, mB0);
        f32x16 st1 = maskinit(mA1, mB1);

        // prefetch next chunk
        if (ch < 15) {
            kG0 = *(const uint4*)(kgp + (size_t)(ch + 1) * 64 * HD);
            kG1 = *(const uint4*)(kgp + (size_t)(ch + 1) * 64 * HD + 8);
            vG0 = *(const uint4*)(vgp + (ch + 1) * 64);
            vG1 = *(const uint4*)(vgp + (ch + 1) * 64 + 8);
            const u16* mnext = mrow + (ch + 1) * 64;
            mA0 = *(const uint4*)(mnext);
            mB0 = *(const uint4*)(mnext + 8);
            mA1 = *(const uint4*)(mnext + 32);
            mB1 = *(const uint4*)(mnext + 40);
        }

        // S^T(log2) = K · Q^T + mask
#pragma unroll
        for (int s = 0; s < 4; ++s) {
            const int g = ((s * 2 + half) ^ q7) * 8;
            bf16x8 ka0 = *(const bf16x8*)&Ks[cur][l31 * 64 + g];
            bf16x8 ka1 = *(const bf16x8*)&Ks[cur][(32 + l31) * 64 + g];
            st0 = __builtin_amdgcn_mfma_f32_32x32x16_bf16(ka0, qb[s], st0, 0, 0, 0);
            st1 = __builtin_amdgcn_mfma_f32_32x32x16_bf16(ka1, qb[s], st1, 0, 0, 0);
        }

        if (ch < 15) {
            *(uint4*)&Ks[1 - cur][srow * 64 + swc0] = kG0;
            *(uint4*)&Ks[1 - cur][srow * 64 + swc1] = kG1;
            *(uint4*)&Vs[1 - cur][srow * 64 + swc0] = vG0;
            *(uint4*)&Vs[1 - cur][srow * 64 + swc1] = vG1;
        }

        // p = exp2(s); sigma-contiguous pack: 2x uint4 per key-tile
#pragma unroll
        for (int tile = 0; tile < 2; ++tile) {
            const f32x16 st = tile ? st1 : st0;
            float p[16];
#pragma unroll
            for (int r = 0; r < 16; ++r) p[r] = EXP2(st[r]);
            float ps = 0.f;
#pragma unroll
            for (int r = 0; r < 16; ++r) ps += p[r];
            lrow += ps;
            uint4 w0, w1;
            w0.x = cvtpk(p[0], p[1]);   w0.y = cvtpk(p[2], p[3]);
            w0.z = cvtpk(p[4], p[5]);   w0.w = cvtpk(p[6], p[7]);
            w1.x = cvtpk(p[8], p[9]);   w1.y = cvtpk(p[10], p[11]);
            w1.z = cvtpk(p[12], p[13]); w1.w = cvtpk(p[14], p[15]);
            const int g = tile * 4 + half * 2;
            *(uint4*)&Ps[qrow * 64 + ((g ^ q7) * 8)]       = w0;
            *(uint4*)&Ps[qrow * 64 + (((g + 1) ^ q7) * 8)] = w1;
        }

        // O^T += V^T · P^T  (wave-private Ps rows: no barrier)
#pragma unroll
        for (int s = 0; s < 4; ++s) {
            const int g = ((s * 2 + half) ^ q7) * 8;
            bf16x8 pb = *(const bf16x8*)&Ps[qrow * 64 + g];
            bf16x8 va0 = *(const bf16x8*)&Vs[cur][l31 * 64 + g];
            bf16x8 va1 = *(const bf16x8*)&Vs[cur][(32 + l31) * 64 + g];
            O0 = __builtin_amdgcn_mfma_f32_32x32x16_bf16(va0, pb, O0, 0, 0, 0);
            O1 = __builtin_amdgcn_mfma_f32_32x32x16_bf16(va1, pb, O1, 0, 0, 0);
        }
        __syncthreads();
    }

    // l: lanes l and l+32 hold disjoint key subsets of the same q
    lrow += __shfl_xor(lrow, 32, 64);
    const float inv = 1.0f / lrow;

    float* orow = out + (rowbase + n0 + qrow) * HD + colbase;
#pragma unroll
    for (int g = 0; g < 4; ++g) {
        const int d0 = 4 * half + 8 * g;
        float4 o0, o1;
        o0.x = O0[4 * g + 0] * inv; o0.y = O0[4 * g + 1] * inv;
        o0.z = O0[4 * g + 2] * inv; o0.w = O0[4 * g + 3] * inv;
        o1.x = O1[4 * g + 0] * inv; o1.y = O1[4 * g + 1] * inv;
        o1.z = O1[4 * g + 2] * inv; o1.w = O1[4 * g + 3] * inv;
        *(float4*)(orow + d0)      = o0;
        *(float4*)(orow + 32 + d0) = o1;
    }
}

// ============================================================
extern "C" void kernel_launch(void* const* d_in, const int* in_sizes, int n_in,
                              void* d_out, int out_size, void* d_ws, size_t ws_size,
                              hipStream_t stream) {
    const int*   adj = (const int*)d_in[0];
    const float* h   = (const float*)d_in[1];
    const float* Wq  = (const float*)d_in[2];
    const float* bq  = (const float*)d_in[3];
    const float* Wk  = (const float*)d_in[4];
    const float* bk  = (const float*)d_in[5];
    const float* Wv  = (const float*)d_in[6];
    const float* bv  = (const float*)d_in[7];
    float* outp = (float*)d_out;

    u16* Wt    = (u16*)d_ws;                                 // 3*512*256 u16
    u16* Qg    = Wt + (size_t)3 * HD * IN_DIM;               // 4 Mi u16 each
    u16* Kg    = Qg + (size_t)BATCH * NSEQ * HD;
    u16* Vtg   = Kg + (size_t)BATCH * NSEQ * HD;
    u16* Madd2 = Vtg + (size_t)BATCH * NSEQ * HD;            // 1 Mi u16

    wtrans_kernel<<<96, 256, 0, stream>>>(Wq, Wk, Wv, Wt);
    gemm_mask_kernel<<<dim3(BATCH * NSEQ / 64, 10), 256, 0, stream>>>(
        h, Wt, adj, bq, bk, bv, Qg, Kg, Vtg, Madd2);
    attn_kernel<<<dim3(BATCH * NHEADS, NSEQ / 128), 256, 0, stream>>>(
        Madd2, Qg, Kg, Vtg, outp);
}